// Round 5
// baseline (912.710 us; speedup 1.0000x reference)
//
#include <hip/hip_runtime.h>

#define Adim 4096
#define HD 128
#define TSTEPS 30
#define NROWS 24576
#define RBLK 48
#define NBLKS 512           // NROWS / RBLK  -> exactly 2 rounds per CU
#define DT_C 0.2f
#define SQDT_C 0.44721359549995794f
#define LN_EPS 1e-5f

#define PI_OFF   2949120    // 6*4096*30*4
#define MASK_OFF 2973696    // PI_OFF + 24576

typedef unsigned short u16;
typedef __bf16 bf16x8 __attribute__((ext_vector_type(8)));
typedef float f32x4 __attribute__((ext_vector_type(4)));

__device__ __forceinline__ u16 f2bf(float x){
    unsigned u = __builtin_bit_cast(unsigned, x);
    u = (u + 0x7fffu + ((u >> 16) & 1u)) >> 16;
    return (u16)u;
}
__device__ __forceinline__ float bf2f(unsigned h){
    unsigned u = (h & 0xffffu) << 16;
    return __builtin_bit_cast(float, u);
}
__device__ __forceinline__ unsigned pack2(float a, float b){
    unsigned r;
    asm("v_cvt_pk_bf16_f32 %0, %1, %2" : "=v"(r) : "v"(a), "v"(b));
    return r;
}
__device__ __forceinline__ float tanh_f(float x){
    return 1.0f - 2.0f / (1.0f + __expf(2.0f * x));
}
__device__ __forceinline__ float sigm_f(float x){
    return 1.0f / (1.0f + __expf(-x));
}
#define SWZ(r,k) ((k) ^ (((r)&7)<<3))
#define MFMA(A,B,C) __builtin_amdgcn_mfma_f32_16x16x32_bf16(A, B, C, 0, 0, 0)

// ---- per-wave weight fragments: 16 output channels per wave ----
__device__ __forceinline__ void loadW(const u16* __restrict__ img, int lane, int wid,
                                      bf16x8 W[4]) {
    const int c = wid*16 + (lane & 15);
    const int kq = lane >> 4;
#pragma unroll
    for (int kk = 0; kk < 4; ++kk)
        W[kk] = *reinterpret_cast<const bf16x8*>(img + c*HD + SWZ(c, kk*32 + kq*8));
}

// ---- GEMMs (swapped): D[c][r] = sum_k W[c][k] act[r][k]; 48 rows = 3 tiles ----
__device__ __forceinline__ void gemm1(const u16* __restrict__ act, const bf16x8 (&W)[4],
                                      int lane, f32x4 acc[3]) {
    const int rl = lane & 15, kq = lane >> 4;
#pragma unroll
    for (int tr = 0; tr < 3; ++tr) {
        const int r = tr*16 + rl;
        const u16* arow = act + r*HD;
        f32x4 a = {0.f,0.f,0.f,0.f};
#pragma unroll
        for (int kk = 0; kk < 4; ++kk) {
            bf16x8 bf = *reinterpret_cast<const bf16x8*>(arow + SWZ(r, kk*32 + kq*8));
            a = MFMA(W[kk], bf, a);
        }
        acc[tr] = a;
    }
}
__device__ __forceinline__ void gemm2(const u16* __restrict__ act,
                                      const bf16x8 (&Wx)[4], const bf16x8 (&Wy)[4],
                                      int lane, f32x4 accX[3], f32x4 accY[3]) {
    const int rl = lane & 15, kq = lane >> 4;
#pragma unroll
    for (int tr = 0; tr < 3; ++tr) {
        const int r = tr*16 + rl;
        const u16* arow = act + r*HD;
        f32x4 ax = {0.f,0.f,0.f,0.f}, ay = {0.f,0.f,0.f,0.f};
#pragma unroll
        for (int kk = 0; kk < 4; ++kk) {
            bf16x8 bf = *reinterpret_cast<const bf16x8*>(arow + SWZ(r, kk*32 + kq*8));
            ax = MFMA(Wx[kk], bf, ax);
            ay = MFMA(Wy[kk], bf, ay);
        }
        accX[tr] = ax; accY[tr] = ay;
    }
}

// ---- epilogues: lane holds 3 row-tiles, 4 consecutive channels ----
__device__ __forceinline__ void epiT(const f32x4 acc[3], const float b[4],
                                     u16* dst, int lane, int wid) {
    const int c0 = wid*16 + ((lane>>4)<<2);
    const int rl = lane & 15;
#pragma unroll
    for (int tr = 0; tr < 3; ++tr) {
        int r = tr*16 + rl;
        float v0 = tanh_f(acc[tr][0] + b[0]);
        float v1 = tanh_f(acc[tr][1] + b[1]);
        float v2 = tanh_f(acc[tr][2] + b[2]);
        float v3 = tanh_f(acc[tr][3] + b[3]);
        uint2 pk = { pack2(v0, v1), pack2(v2, v3) };
        *reinterpret_cast<uint2*>(dst + r*HD + SWZ(r, c0)) = pk;
    }
}
__device__ __forceinline__ void epiN(const f32x4 acc[3], const float b[4],
                                     u16* dst, int lane, int wid) {
    const int c0 = wid*16 + ((lane>>4)<<2);
    const int rl = lane & 15;
#pragma unroll
    for (int tr = 0; tr < 3; ++tr) {
        int r = tr*16 + rl;
        uint2 pk = { pack2(acc[tr][0]+b[0], acc[tr][1]+b[1]),
                     pack2(acc[tr][2]+b[2], acc[tr][3]+b[3]) };
        *reinterpret_cast<uint2*>(dst + r*HD + SWZ(r, c0)) = pk;
    }
}
__device__ __forceinline__ void epiF(const f32x4 acc[3], const float* __restrict__ bias,
                                     float* dst, int lane, int wid) {
    const int c0 = wid*16 + ((lane>>4)<<2);
    const int rl = lane & 15;
    float4 b4 = *reinterpret_cast<const float4*>(bias + c0);
#pragma unroll
    for (int tr = 0; tr < 3; ++tr) {
        int r = tr*16 + rl;
        float4 v = { acc[tr][0]+b4.x, acc[tr][1]+b4.y, acc[tr][2]+b4.z, acc[tr][3]+b4.w };
        *reinterpret_cast<float4*>(dst + r*HD + c0) = v;
    }
}

// ---- prologue GEMM over Xc (lda=256) ----
__device__ __forceinline__ void gemmX(const u16* __restrict__ Xc, int kBase,
                                      const u16* __restrict__ img,
                                      int lane, int wid, f32x4 acc[3], bool init) {
    bf16x8 W[4]; loadW(img, lane, wid, W);
    const int rl = lane & 15, kq = lane >> 4;
#pragma unroll
    for (int tr = 0; tr < 3; ++tr) {
        const int r = tr*16 + rl;
        const u16* arow = Xc + r*256;
        f32x4 a = init ? f32x4{0.f,0.f,0.f,0.f} : acc[tr];
#pragma unroll
        for (int kk = 0; kk < 4; ++kk) {
            bf16x8 bf = *reinterpret_cast<const bf16x8*>(arow + SWZ(r, kBase + kk*32 + kq*8));
            a = MFMA(W[kk], bf, a);
        }
        acc[tr] = a;
    }
}

// ---- LN + relu + 2-wide head; 4 lanes/row, 32 ch/lane ----
__device__ __forceinline__ void head_ln4(const u16* __restrict__ src,
                                         const float4* __restrict__ pp4,
                                         float b20, float b21, int elu, int off,
                                         int idx, float* __restrict__ outStage)
{
    int row = idx >> 2, part = idx & 3;
    int c0 = part * 32;
    float v[32];
#pragma unroll
    for (int u = 0; u < 4; ++u) {
        uint4 p = *reinterpret_cast<const uint4*>(src + row*HD + SWZ(row, c0 + u*8));
        v[u*8+0]=bf2f(p.x); v[u*8+1]=bf2f(p.x>>16);
        v[u*8+2]=bf2f(p.y); v[u*8+3]=bf2f(p.y>>16);
        v[u*8+4]=bf2f(p.z); v[u*8+5]=bf2f(p.z>>16);
        v[u*8+6]=bf2f(p.w); v[u*8+7]=bf2f(p.w>>16);
    }
    float s = 0.f, sq = 0.f;
#pragma unroll
    for (int i = 0; i < 32; ++i){ s += v[i]; sq += v[i]*v[i]; }
    s += __shfl_xor(s,1); sq += __shfl_xor(sq,1);
    s += __shfl_xor(s,2); sq += __shfl_xor(sq,2);
    float mu = s * (1.f/128.f);
    float rstd = rsqrtf(sq*(1.f/128.f) - mu*mu + LN_EPS);
    float a0 = 0.f, a1 = 0.f;
#pragma unroll
    for (int i = 0; i < 32; ++i){
        int c = c0 + i;
        float4 p = pp4[c ^ ((c>>4)&7)];
        float h = (v[i]-mu)*rstd*p.x + p.y;
        h = fmaxf(h, 0.f);
        a0 += h * p.z; a1 += h * p.w;
    }
    a0 += __shfl_xor(a0,1); a1 += __shfl_xor(a1,1);
    a0 += __shfl_xor(a0,2); a1 += __shfl_xor(a1,2);
    if (part == 0){
        a0 += b20; a1 += b21;
        if (elu){
            a0 = (a0 > 0.f ? a0 : __expf(a0)-1.f) + 1.001f;
            a1 = (a1 > 0.f ? a1 : __expf(a1)-1.f) + 1.001f;
        }
        outStage[row*4 + off]   = a0;
        outStage[row*4 + off+1] = a1;
    }
}

// ---------- weight image prep: f32 -> bf16, transposed, swizzled ----------
__global__ void prep_w(const float* __restrict__ fw1, const float* __restrict__ fw2,
                       const float* __restrict__ fw3, const float* __restrict__ gw1,
                       const float* __restrict__ gw2, const float* __restrict__ dw1,
                       const float* __restrict__ sw1, const float* __restrict__ aw,
                       const float* __restrict__ pw1, u16* __restrict__ ws)
{
    int img = blockIdx.y;
    int idx = blockIdx.x * 256 + threadIdx.x;   // 0..16383
    int k = idx >> 7, j = idx & 127;
    const float* W = fw1; int sr = k;
    switch (img) {
        case 0: W = fw1; break;  case 1: W = fw2; break;  case 2: W = fw3; break;
        case 3: W = gw1; break;  case 4: W = gw2; break;
        case 5: W = dw1; break;  case 6: W = sw1; break;
        case 7: W = aw;  break;  case 8: W = aw;  sr = k + 128; break;
        case 9: W = pw1; break;  case 10: W = pw1; sr = k + 128; break;
    }
    ws[(size_t)img*16384 + j*128 + SWZ(j, k)] = f2bf(W[(size_t)sr*128 + j]);
}

// ---------- final output reorder: ws [blk][tt][row][4] -> loc_out [gr][tt][4] ----------
__global__ void reorder_out(const float* __restrict__ wsOut, float* __restrict__ outp)
{
    __shared__ float tile[5760];
    int b = blockIdx.x;
    int tid = threadIdx.x;                    // 192 threads
    const float* src = wsOut + (size_t)b*5760;
    int row = tid >> 2, c = tid & 3;
#pragma unroll
    for (int j = 0; j < TSTEPS; ++j)
        tile[row*120 + j*4 + c] = src[j*192 + tid];
    __syncthreads();
    float* dst = outp + (size_t)b*5760;
#pragma unroll
    for (int j = 0; j < TSTEPS; ++j)
        dst[j*192 + tid] = tile[j*192 + tid];
}

// ---------- the fused persistent kernel ----------
__global__ __launch_bounds__(512, 2) void sde_fused(
    const float* __restrict__ lE, const float* __restrict__ gE,
    const float* __restrict__ noise,
    const float* __restrict__ aggr_b, const float* __restrict__ aggr_g, const float* __restrict__ aggr_be,
    const float* __restrict__ fw1, const float* __restrict__ fb1,
    const float* __restrict__ fb2, const float* __restrict__ fb3,
    const float* __restrict__ gw1, const float* __restrict__ gb1,
    const float* __restrict__ gb2, const float* __restrict__ gw3, const float* __restrict__ gb3,
    const float* __restrict__ db1, const float* __restrict__ dg, const float* __restrict__ dbe,
    const float* __restrict__ dw2, const float* __restrict__ db2,
    const float* __restrict__ sb1, const float* __restrict__ sg, const float* __restrict__ sbe,
    const float* __restrict__ sw2, const float* __restrict__ sb2,
    const float* __restrict__ pb1, const float* __restrict__ pg, const float* __restrict__ pbe,
    const float* __restrict__ pw2, const float* __restrict__ pb2,
    const unsigned char* __restrict__ pmask,
    const u16* __restrict__ wimg,
    float* __restrict__ wsOut,
    float* __restrict__ outp)
{
    // LDS: Sb@0 Ab@12K Bb@24K Cb@36K Db@48K Eb@60K (12KB each, 48x128 bf16)
    //      gpart @72K (48x34 f32, stride 34: conflict-free + 8B-aligned float2)
    //      ppd @78.4K, pps @80.4K (float4 swizzled), outStage @82.4K (192 f32)
    // prologue aliases: Xc (24K) over Db+Eb; preLN f32 (24K) over Ab+Bb
    __shared__ __align__(16) unsigned char SMEM[85120];
    u16*  Sb    = (u16*)SMEM;
    u16*  Ab    = (u16*)(SMEM + 12288);
    u16*  Bb    = (u16*)(SMEM + 24576);
    u16*  Cb    = (u16*)(SMEM + 36864);
    u16*  Db    = (u16*)(SMEM + 49152);
    u16*  Eb    = (u16*)(SMEM + 61440);
    float* gpart = (float*)(SMEM + 73728);     // 48*34*4 = 6528
    float4* ppd = (float4*)(SMEM + 80256);
    float4* pps = (float4*)(SMEM + 82304);
    float* outStage = (float*)(SMEM + 84352);  // 192 floats
    u16*  Xc    = (u16*)(SMEM + 49152);
    float* preLN = (float*)(SMEM + 12288);

    const int tid  = threadIdx.x;
    const int lane = tid & 63;
    const int wid  = tid >> 6;
    const int bid  = blockIdx.x;
    const int r0   = bid * RBLK;
    const int rl   = lane & 15;
    const int c0e  = wid*16 + ((lane>>4)<<2);   // this lane's 4 output channels

    // -------- stage params + Xc --------
    if (tid < 128) {
        int cs = tid ^ ((tid >> 4) & 7);
        ppd[cs] = make_float4(dg[tid], dbe[tid], dw2[2*tid], dw2[2*tid+1]);
        pps[cs] = make_float4(sg[tid], sbe[tid], sw2[2*tid], sw2[2*tid+1]);
    }
#pragma unroll
    for (int i = 0; i < 3; ++i) {
        int gidx = i*512 + tid;             // 0..1535
        int r = gidx >> 5;
        int k = (gidx & 31) * 8;
        int gr = r0 + r;
        const float* src = (k < HD) ? (gE + (size_t)gr*HD + k)
                                    : (lE + (size_t)(gr & (Adim-1))*HD + (k - HD));
        float4 v0 = reinterpret_cast<const float4*>(src)[0];
        float4 v1 = reinterpret_cast<const float4*>(src)[1];
        uint4 pk = { pack2(v0.x, v0.y), pack2(v0.z, v0.w),
                     pack2(v1.x, v1.y), pack2(v1.z, v1.w) };
        *reinterpret_cast<uint4*>(Xc + r*256 + SWZ(r, k)) = pk;
    }
    __syncthreads();

    f32x4 acc3[3];

    // -------- pi head --------
    gemmX(Xc, 0,   wimg + 10*16384, lane, wid, acc3, true);   // ge part
    gemmX(Xc, 128, wimg + 9*16384,  lane, wid, acc3, false);  // le part
    epiF(acc3, pb1, preLN, lane, wid);
    __syncthreads();
    if (tid < 384) {
        int row = tid >> 3, sub = tid & 7;
        int c0 = sub * 16;
        const float* yr = preLN + row*HD + c0;
        float v[16]; float s = 0.f, sq = 0.f;
#pragma unroll
        for (int i = 0; i < 16; ++i){ float x = yr[i]; v[i] = x; s += x; sq += x*x; }
        s += __shfl_xor(s,1); sq += __shfl_xor(sq,1);
        s += __shfl_xor(s,2); sq += __shfl_xor(sq,2);
        s += __shfl_xor(s,4); sq += __shfl_xor(sq,4);
        float mu = s*(1.f/128.f);
        float rstd = rsqrtf(sq*(1.f/128.f) - mu*mu + LN_EPS);
        float a0 = 0.f;
#pragma unroll
        for (int i = 0; i < 16; ++i){
            int cc = c0 + i;
            float h = (v[i]-mu)*rstd*pg[cc] + pbe[cc];
            a0 += fmaxf(h, 0.f) * pw2[cc];
        }
        a0 += __shfl_xor(a0,1); a0 += __shfl_xor(a0,2); a0 += __shfl_xor(a0,4);
        if (sub == 0) {
            int gr = r0 + row;
            outp[PI_OFF + (size_t)(gr & (Adim-1))*6 + (gr >> 12)] = a0 + pb2[0];
        }
    }
    if (tid < RBLK) {              // reg_mask (rows with m==0)
        int gr = r0 + tid;
        if (gr < Adim) {
            const unsigned char* pm = pmask + (size_t)gr*50 + 20;
            float* o = outp + MASK_OFF + (size_t)gr*TSTEPS;
#pragma unroll
            for (int i = 0; i < TSTEPS; ++i) o[i] = pm[i] ? 0.f : 1.f;
        }
    }
    __syncthreads();

    // -------- aggr head -> h0 --------
    gemmX(Xc, 0,   wimg + 7*16384, lane, wid, acc3, true);
    gemmX(Xc, 128, wimg + 8*16384, lane, wid, acc3, false);
    __syncthreads();
    epiF(acc3, aggr_b, preLN, lane, wid);
    __syncthreads();
    if (tid < 384) {               // LN + relu -> preLN (f32) + Sb (bf16)
        int row = tid >> 3, sub = tid & 7;
        int c0 = sub * 16;
        float* yr = preLN + row*HD + c0;
        float v[16]; float s = 0.f, sq = 0.f;
#pragma unroll
        for (int i = 0; i < 16; ++i){ float x = yr[i]; v[i] = x; s += x; sq += x*x; }
        s += __shfl_xor(s,1); sq += __shfl_xor(sq,1);
        s += __shfl_xor(s,2); sq += __shfl_xor(sq,2);
        s += __shfl_xor(s,4); sq += __shfl_xor(sq,4);
        float mu = s*(1.f/128.f);
        float rstd = rsqrtf(sq*(1.f/128.f) - mu*mu + LN_EPS);
#pragma unroll
        for (int i = 0; i < 16; ++i){
            int cc = c0 + i;
            float h = (v[i]-mu)*rstd*aggr_g[cc] + aggr_be[cc];
            v[i] = fmaxf(h, 0.f);
        }
#pragma unroll
        for (int u = 0; u < 4; ++u)
            *reinterpret_cast<float4*>(yr + u*4) = *(float4*)&v[u*4];
        uint4 pk0 = { pack2(v[0],v[1]), pack2(v[2],v[3]),
                      pack2(v[4],v[5]), pack2(v[6],v[7]) };
        uint4 pk1 = { pack2(v[8],v[9]), pack2(v[10],v[11]),
                      pack2(v[12],v[13]), pack2(v[14],v[15]) };
        *reinterpret_cast<uint4*>(&Sb[row*HD + SWZ(row, c0)])   = pk0;
        *reinterpret_cast<uint4*>(&Sb[row*HD + SWZ(row, c0+8)]) = pk1;
    }
    __syncthreads();

    // -------- state y into registers (MFMA D-layout: rows {rl,16+rl,32+rl} x c0e..+3) --------
    float y[12];
#pragma unroll
    for (int tr = 0; tr < 3; ++tr) {
        float4 t = *reinterpret_cast<const float4*>(preLN + (tr*16+rl)*HD + c0e);
        y[tr*4+0]=t.x; y[tr*4+1]=t.y; y[tr*4+2]=t.z; y[tr*4+3]=t.w;
    }

    // -------- loop weights into registers --------
    bf16x8 WF1[4], WG1[4], WF2[4], WG2[4], WF3[4], WD1[4], WS1[4];
    loadW(wimg + 0*16384, lane, wid, WF1);
    loadW(wimg + 3*16384, lane, wid, WG1);
    loadW(wimg + 1*16384, lane, wid, WF2);
    loadW(wimg + 4*16384, lane, wid, WG2);
    loadW(wimg + 2*16384, lane, wid, WF3);
    loadW(wimg + 5*16384, lane, wid, WD1);
    loadW(wimg + 6*16384, lane, wid, WS1);

    float fb2c[4], gb2c[4], fb3c[4], db1c[4], sb1c[4], gw3c[4];
    float fb1c[4], gb1c[4], fw1s[4], fw1cc[4], gw1s[4], gw1cc[4];
#pragma unroll
    for (int q = 0; q < 4; ++q) {
        int c = c0e + q;
        fb2c[q]=fb2[c]; gb2c[q]=gb2[c]; fb3c[q]=fb3[c]; db1c[q]=db1[c]; sb1c[q]=sb1[c];
        fb1c[q]=fb1[c]; gb1c[q]=gb1[c]; gw3c[q]=gw3[c];
        fw1s[q]=fw1[128*HD+c]; fw1cc[q]=fw1[129*HD+c];
        gw1s[q]=gw1[128*HD+c]; gw1cc[q]=gw1[129*HD+c];
    }
    const float db20 = db2[0], db21 = db2[1];
    const float sb20 = sb2[0], sb21 = sb2[1];
    const float gb3v = gb3[0];
    __syncthreads();

    // -------- Euler-Maruyama scan: 3 barriers/step --------
    float4 nz[3];
    for (int k = 0; k < TSTEPS; ++k) {
        // PhA: L1f,L1g on Sb(y_k); noise prefetch (D-layout); flush out(k-2)
        {
            float t = k * DT_C;
            float st = __sinf(t), ct = __cosf(t);
            float bF[4], bG[4];
#pragma unroll
            for (int q = 0; q < 4; ++q) {
                bF[q] = fb1c[q] + st*fw1s[q] + ct*fw1cc[q];
                bG[q] = gb1c[q] + st*gw1s[q] + ct*gw1cc[q];
            }
            f32x4 aF[3], aG[3];
            gemm2(Sb, WF1, WG1, lane, aF, aG);
            epiT(aF, bF, Ab, lane, wid);
            epiT(aG, bG, Bb, lane, wid);
        }
#pragma unroll
        for (int tr = 0; tr < 3; ++tr)
            nz[tr] = *reinterpret_cast<const float4*>(
                noise + ((size_t)k*NROWS + r0 + tr*16 + rl)*HD + c0e);
        if (k >= 2 && tid < 192)
            wsOut[((size_t)bid*TSTEPS + (k-2))*192 + tid] = outStage[tid];
        __syncthreads();

        // PhB: L2f(Ab->Cb); L2g(Bb->gpart partials, no LDS act); D1,S1(Sb->Db,Eb)
        {
            f32x4 a1[3];
            gemm1(Ab, WF2, lane, a1);
            epiT(a1, fb2c, Cb, lane, wid);
            gemm1(Bb, WG2, lane, a1);
            const int kq = lane >> 4;
#pragma unroll
            for (int tr = 0; tr < 3; ++tr) {
                float p = tanh_f(a1[tr][0]+gb2c[0]) * gw3c[0]
                        + tanh_f(a1[tr][1]+gb2c[1]) * gw3c[1]
                        + tanh_f(a1[tr][2]+gb2c[2]) * gw3c[2]
                        + tanh_f(a1[tr][3]+gb2c[3]) * gw3c[3];
                gpart[(tr*16+rl)*34 + wid*4 + kq] = p;
            }
        }
        if (k >= 1) {
            f32x4 aD[3], aS[3];
            gemm2(Sb, WD1, WS1, lane, aD, aS);
            epiN(aD, db1c, Db, lane, wid);
            epiN(aS, sb1c, Eb, lane, wid);
        }
        __syncthreads();

        // PhC: L3f(Cb) drift; gpart reduce -> g; in-register Euler update -> Sb; heads
        {
            f32x4 aD3[3];
            gemm1(Cb, WF3, lane, aD3);
            const int kq = lane >> 4;
            float g[3];
#pragma unroll
            for (int tr = 0; tr < 3; ++tr) {
                const float* gp = gpart + (tr*16+rl)*34 + kq*8;
                float2 u0 = *reinterpret_cast<const float2*>(gp);
                float2 u1 = *reinterpret_cast<const float2*>(gp+2);
                float2 u2 = *reinterpret_cast<const float2*>(gp+4);
                float2 u3 = *reinterpret_cast<const float2*>(gp+6);
                float s = u0.x+u0.y+u1.x+u1.y+u2.x+u2.y+u3.x+u3.y;
                s += __shfl_xor(s, 16);
                s += __shfl_xor(s, 32);
                g[tr] = sigm_f(s + gb3v) * SQDT_C;
            }
#pragma unroll
            for (int tr = 0; tr < 3; ++tr) {
                int row = tr*16 + rl;
                y[tr*4+0] += (aD3[tr][0]+fb3c[0])*DT_C + g[tr]*nz[tr].x;
                y[tr*4+1] += (aD3[tr][1]+fb3c[1])*DT_C + g[tr]*nz[tr].y;
                y[tr*4+2] += (aD3[tr][2]+fb3c[2])*DT_C + g[tr]*nz[tr].z;
                y[tr*4+3] += (aD3[tr][3]+fb3c[3])*DT_C + g[tr]*nz[tr].w;
                uint2 pk = { pack2(y[tr*4+0],y[tr*4+1]), pack2(y[tr*4+2],y[tr*4+3]) };
                *reinterpret_cast<uint2*>(Sb + row*HD + SWZ(row, c0e)) = pk;
            }
        }
        if (k >= 1) {
            if (tid < 192)      head_ln4(Db, ppd, db20, db21, 0, 0, tid, outStage);
            else if (tid < 384) head_ln4(Eb, pps, sb20, sb21, 1, 2, tid-192, outStage);
        }
        __syncthreads();
    }

    // -------- tail: flush out(28); D/S on final state; heads -> out(29) --------
    if (tid < 192)
        wsOut[((size_t)bid*TSTEPS + (TSTEPS-2))*192 + tid] = outStage[tid];
    {
        f32x4 aD[3], aS[3];
        gemm2(Sb, WD1, WS1, lane, aD, aS);
        epiN(aD, db1c, Db, lane, wid);
        epiN(aS, sb1c, Eb, lane, wid);
    }
    __syncthreads();
    if (tid < 192)      head_ln4(Db, ppd, db20, db21, 0, 0, tid, outStage);
    else if (tid < 384) head_ln4(Eb, pps, sb20, sb21, 1, 2, tid-192, outStage);
    __syncthreads();
    if (tid < 192)
        wsOut[((size_t)bid*TSTEPS + (TSTEPS-1))*192 + tid] = outStage[tid];
}

extern "C" void kernel_launch(void* const* d_in, const int* in_sizes, int n_in,
                              void* d_out, int out_size, void* d_ws, size_t ws_size,
                              hipStream_t stream) {
    const float* lE      = (const float*)d_in[0];
    const float* gE      = (const float*)d_in[1];
    const float* noise   = (const float*)d_in[2];
    const float* aggr_w  = (const float*)d_in[3];
    const float* aggr_b  = (const float*)d_in[4];
    const float* aggr_g  = (const float*)d_in[5];
    const float* aggr_be = (const float*)d_in[6];
    const float* fw1 = (const float*)d_in[7];
    const float* fb1 = (const float*)d_in[8];
    const float* fw2 = (const float*)d_in[9];
    const float* fb2 = (const float*)d_in[10];
    const float* fw3 = (const float*)d_in[11];
    const float* fb3 = (const float*)d_in[12];
    const float* gw1 = (const float*)d_in[13];
    const float* gb1 = (const float*)d_in[14];
    const float* gw2 = (const float*)d_in[15];
    const float* gb2 = (const float*)d_in[16];
    const float* gw3 = (const float*)d_in[17];
    const float* gb3 = (const float*)d_in[18];
    const float* dw1 = (const float*)d_in[19];
    const float* db1 = (const float*)d_in[20];
    const float* dg  = (const float*)d_in[21];
    const float* dbe = (const float*)d_in[22];
    const float* dw2 = (const float*)d_in[23];
    const float* db2 = (const float*)d_in[24];
    const float* sw1 = (const float*)d_in[25];
    const float* sb1 = (const float*)d_in[26];
    const float* sg  = (const float*)d_in[27];
    const float* sbe = (const float*)d_in[28];
    const float* sw2 = (const float*)d_in[29];
    const float* sb2 = (const float*)d_in[30];
    const float* pw1 = (const float*)d_in[31];
    const float* pb1 = (const float*)d_in[32];
    const float* pg  = (const float*)d_in[33];
    const float* pbe = (const float*)d_in[34];
    const float* pw2 = (const float*)d_in[35];
    const float* pb2 = (const float*)d_in[36];
    const unsigned char* pmask = (const unsigned char*)d_in[37];
    float* outp = (float*)d_out;
    u16* wimg = (u16*)d_ws;                                  // 352 KB
    float* wsOut = (float*)((char*)d_ws + 360448);           // 512*5760 floats = 11.8 MB

    prep_w<<<dim3(64, 11), 256, 0, stream>>>(fw1, fw2, fw3, gw1, gw2, dw1, sw1,
                                             aggr_w, pw1, wimg);
    sde_fused<<<NBLKS, 512, 0, stream>>>(
        lE, gE, noise, aggr_b, aggr_g, aggr_be,
        fw1, fb1, fb2, fb3,
        gw1, gb1, gb2, gw3, gb3,
        db1, dg, dbe, dw2, db2,
        sb1, sg, sbe, sw2, sb2,
        pb1, pg, pbe, pw2, pb2,
        pmask, wimg, wsOut, outp);
    reorder_out<<<NBLKS, 192, 0, stream>>>(wsOut, outp);
}